// Round 1
// baseline (627.371 us; speedup 1.0000x reference)
//
#include <hip/hip_runtime.h>

#define T_LEN 1024
#define NBATCH 256
#define HDIM 12

// ---------- helpers ----------
#if __has_builtin(__builtin_amdgcn_exp2f)
#define EXP2F(x) __builtin_amdgcn_exp2f(x)
#else
#define EXP2F(x) exp2f(x)
#endif
#if __has_builtin(__builtin_amdgcn_rcpf)
#define RCPF(x) __builtin_amdgcn_rcpf(x)
#else
#define RCPF(x) (1.0f / (x))
#endif

__device__ __forceinline__ float rl(float v, int lane) {
#if __has_builtin(__builtin_amdgcn_readlane)
  return __int_as_float(__builtin_amdgcn_readlane(__float_as_int(v), lane));
#else
  return __shfl(v, lane, 64);
#endif
}

template <int Q>
__device__ __forceinline__ float qb(float v) {
#if __has_builtin(__builtin_amdgcn_mov_dpp)
  return __int_as_float(__builtin_amdgcn_mov_dpp(__float_as_int(v), Q * 0x55, 0xF, 0xF, true));
#else
  return __shfl(v, (threadIdx.x & ~3) | Q, 64);
#endif
}

// sigmoid (c1=1,c0=0,k=-log2e) or tanh (c1=2,c0=-1,k=-2log2e): c1/(1+exp2(k*x))+c0
__device__ __forceinline__ float nl_gate(float x, float kq, float c1, float c0) {
  float e = EXP2F(kq * x);
  float r = RCPF(1.0f + e);
  return fmaf(c1, r, c0);
}
__device__ __forceinline__ float tanh_fast(float x) {
  float e = EXP2F(-2.8853900817779268f * x);
  float r = RCPF(1.0f + e);
  return fmaf(2.0f, r, -1.0f);
}

__device__ __forceinline__ unsigned short f2bf(float f) {  // RNE f32->bf16
  unsigned u = __float_as_uint(f);
  u = u + 0x7fffu + ((u >> 16) & 1u);
  return (unsigned short)(u >> 16);
}
__device__ __forceinline__ float bflo(unsigned w) { return __uint_as_float(w << 16); }
__device__ __forceinline__ float bfhi(unsigned w) { return __uint_as_float(w & 0xffff0000u); }

#define LSTM_UPDATE(nv, cv, hq)                   \
  {                                               \
    float si = qb<0>(nv), sf = qb<1>(nv);         \
    float tg = qb<2>(nv), so = qb<3>(nv);         \
    cv = fmaf(sf, cv, si * tg);                   \
    hq = so * tanh_fast(cv);                      \
  }

// ============================================================================
// Kernel 1: fused 3-layer LSTM. One wave per batch element.
// Lane 4j+q computes gate type q (i,f,g,o) of hidden unit j.
// Layers software-pipelined: at superstep s, layer0 does step s, layer1 step
// s-1, layer2 step s-2 (independent chains -> ILP). h broadcast via readlane
// (SGPR), quad combine via DPP. Output x3 layout [T][B][12] (coalesced for k2).
// ============================================================================
__global__ __launch_bounds__(64, 1) void lstm3_kernel(
    const float* __restrict__ mfcc, const float* __restrict__ Wih,
    const float* __restrict__ Whh, const float* __restrict__ bih,
    const float* __restrict__ bhh, float* __restrict__ x3) {
  const int b = blockIdx.x;
  const int lane = threadIdx.x & 63;
  const int j = lane >> 2;
  const int q = lane & 3;
  const int jj = (j < HDIM) ? j : (HDIM - 1);  // lanes j>=12 duplicate row 11 (results unused)
  const int g = q * HDIM + jj;                 // torch gate order i,f,g,o

  float wih[3][HDIM], whh[3][HDIM], bias[3];
#pragma unroll
  for (int l = 0; l < 3; ++l) {
#pragma unroll
    for (int m = 0; m < HDIM; ++m) {
      wih[l][m] = Wih[(l * 48 + g) * HDIM + m];
      whh[l][m] = Whh[(l * 48 + g) * HDIM + m];
    }
    bias[l] = bih[l * 48 + g] + bhh[l * 48 + g];
  }

  const float kq = (q == 2) ? -2.8853900817779268f : -1.4426950408889634f;
  const float c1 = (q == 2) ? 2.0f : 1.0f;
  const float c0 = (q == 2) ? -1.0f : 0.0f;

  float c_l0 = 0.f, c_l1 = 0.f, c_l2 = 0.f;
  float h0s[HDIM], h1s[HDIM], h2s[HDIM];  // wave-uniform (SGPR via readlane)
#pragma unroll
  for (int m = 0; m < HDIM; ++m) { h0s[m] = 0.f; h1s[m] = 0.f; h2s[m] = 0.f; }

  const float4* xp = (const float4*)(mfcc + b * (T_LEN * HDIM));
  float4 xa = xp[0], xb = xp[1], xc = xp[2];  // x(0)
  float* op = x3 + b * HDIM;

  for (int s = 0; s < T_LEN + 2; ++s) {
    // prefetch x(s+1)
    float4 na = make_float4(0.f, 0.f, 0.f, 0.f), nb = na, nc = na;
    if (s + 1 < T_LEN) {
      na = xp[(s + 1) * 3 + 0];
      nb = xp[(s + 1) * 3 + 1];
      nc = xp[(s + 1) * 3 + 2];
    }
    const float xs[HDIM] = {xa.x, xa.y, xa.z, xa.w, xb.x, xb.y,
                            xb.z, xb.w, xc.x, xc.y, xc.z, xc.w};

    const bool v0 = (s < T_LEN);
    const bool v1 = (s >= 1) && (s <= T_LEN);
    const bool v2 = (s >= 2);

    // gate pre-activations for all three (independent) layer-steps
    float a0 = bias[0], a1 = bias[1], a2 = bias[2];
#pragma unroll
    for (int m = 0; m < HDIM; ++m) {
      a0 = fmaf(wih[0][m], xs[m], a0);
      a1 = fmaf(wih[1][m], h0s[m], a1);  // layer1 input = h0(s-1)
      a2 = fmaf(wih[2][m], h1s[m], a2);  // layer2 input = h1(s-2)
    }
#pragma unroll
    for (int m = 0; m < HDIM; ++m) {
      a0 = fmaf(whh[0][m], h0s[m], a0);
      a1 = fmaf(whh[1][m], h1s[m], a1);
      a2 = fmaf(whh[2][m], h2s[m], a2);
    }

    float n0 = nl_gate(a0, kq, c1, c0);
    float n1 = nl_gate(a1, kq, c1, c0);
    float n2 = nl_gate(a2, kq, c1, c0);

    if (v0) {
      float hq0;
      LSTM_UPDATE(n0, c_l0, hq0);
#pragma unroll
      for (int m = 0; m < HDIM; ++m) h0s[m] = rl(hq0, 4 * m);
    }
    if (v1) {
      float hq1;
      LSTM_UPDATE(n1, c_l1, hq1);
#pragma unroll
      for (int m = 0; m < HDIM; ++m) h1s[m] = rl(hq1, 4 * m);
    }
    if (v2) {
      float hq2;
      LSTM_UPDATE(n2, c_l2, hq2);
      if (q == 0 && j < HDIM) op[(s - 2) * (NBATCH * HDIM) + j] = hq2;
#pragma unroll
      for (int m = 0; m < HDIM; ++m) h2s[m] = rl(hq2, 4 * m);
    }
    xa = na; xb = nb; xc = nc;
  }
}

// ============================================================================
// Kernel 2: per-timestep MLP + batch-axis BN (training stats) + lambda
// projection. One block per t, 256 threads. fc1/fc2 biases cancel under BN.
// LDS (55.3KB): h1t bf16[64][256] + w2s bf16[64][128], aliased by p3
// f32[8][256][6] after fc2; plus w3s, stat partials, scale/shift.
// ============================================================================
__global__ __launch_bounds__(256, 2) void mlp_out_kernel(
    const float* __restrict__ x3, const float* __restrict__ mfcc,
    const float* __restrict__ w1, const float* __restrict__ g1,
    const float* __restrict__ be1, const float* __restrict__ w2,
    const float* __restrict__ g2, const float* __restrict__ be2,
    const float* __restrict__ w3, const float* __restrict__ b3,
    const float* __restrict__ WI, float* __restrict__ outp) {
  __shared__ __align__(16) unsigned char smem[55296];
  unsigned short* h1  = (unsigned short*)smem;            // [64][256] bf16
  unsigned short* w2s = (unsigned short*)(smem + 32768);  // [64][128] bf16 (transposed)
  float* p3   = (float*)smem;                             // [8][256][6] (alias)
  float* w3s  = (float*)(smem + 49152);                   // [6][128]
  float* stp  = (float*)(smem + 52224);                   // stat partials
  float* scsh = (float*)(smem + 54272);                   // [128][2] scale/shift

  const int t = blockIdx.x;
  const int tid = threadIdx.x;

  // ---- phase 1: stage w2 (transposed -> [k][c]) and w3 ----
  for (int i = tid; i < 8192; i += 256) {
    int k = i >> 7, c = i & 127;
    w2s[k * 128 + c] = f2bf(w2[c * 64 + k]);
  }
  for (int i = tid; i < 768; i += 256) w3s[i] = w3[i];

  // ---- phase 2: fc1 (bias cancels under BN); each thread = one b ----
  {
    const float4* xp4 = (const float4*)(x3 + t * (NBATCH * HDIM) + tid * HDIM);
    float4 u0 = xp4[0], u1 = xp4[1], u2 = xp4[2];
    const float x[HDIM] = {u0.x, u0.y, u0.z, u0.w, u1.x, u1.y,
                           u1.z, u1.w, u2.x, u2.y, u2.z, u2.w};
#pragma unroll 8
    for (int ch = 0; ch < 64; ++ch) {
      float a = 0.f;
#pragma unroll
      for (int d = 0; d < HDIM; ++d) a = fmaf(w1[ch * HDIM + d], x[d], a);
      h1[ch * 256 + tid] = f2bf(a);
    }
  }
  __syncthreads();

  // ---- phase 3: BN1 stats over b (on the bf16 values: self-consistent) ----
  {
    const int ch = tid & 63, grp = tid >> 6;
    const uint4* rp = (const uint4*)(h1 + ch * 256 + grp * 64);
    float s = 0.f, sq = 0.f;
#pragma unroll
    for (int i = 0; i < 8; ++i) {
      uint4 v = rp[(i + ch) & 7];  // rotate to avoid bank conflicts
      float f0 = bflo(v.x), f1 = bfhi(v.x), f2 = bflo(v.y), f3 = bfhi(v.y);
      float f4 = bflo(v.z), f5 = bfhi(v.z), f6 = bflo(v.w), f7 = bfhi(v.w);
      s += ((f0 + f1) + (f2 + f3)) + ((f4 + f5) + (f6 + f7));
      sq = fmaf(f0, f0, sq); sq = fmaf(f1, f1, sq);
      sq = fmaf(f2, f2, sq); sq = fmaf(f3, f3, sq);
      sq = fmaf(f4, f4, sq); sq = fmaf(f5, f5, sq);
      sq = fmaf(f6, f6, sq); sq = fmaf(f7, f7, sq);
    }
    stp[(ch * 4 + grp) * 2] = s;
    stp[(ch * 4 + grp) * 2 + 1] = sq;
  }
  __syncthreads();
  if (tid < 64) {
    float s = 0.f, sq = 0.f;
#pragma unroll
    for (int gg = 0; gg < 4; ++gg) {
      s += stp[(tid * 4 + gg) * 2];
      sq += stp[(tid * 4 + gg) * 2 + 1];
    }
    float mu = s * (1.f / 256.f);
    float var = fmaf(-mu, mu, sq * (1.f / 256.f));
    float sc = g1[tid] * rsqrtf(var + 1e-5f);
    scsh[tid * 2] = sc;
    scsh[tid * 2 + 1] = fmaf(-sc, mu, be1[tid]);
  }
  __syncthreads();
  // ---- phase 3c: apply BN1 + relu in place ----
  {
    const int ch = tid & 63, grp = tid >> 6;
    const float sc = scsh[ch * 2], sh = scsh[ch * 2 + 1];
    uint4* rp = (uint4*)(h1 + ch * 256 + grp * 64);
#pragma unroll
    for (int i = 0; i < 8; ++i) {
      uint4 v = rp[(i + ch) & 7];
      float f0 = fmaxf(fmaf(sc, bflo(v.x), sh), 0.f);
      float f1 = fmaxf(fmaf(sc, bfhi(v.x), sh), 0.f);
      float f2 = fmaxf(fmaf(sc, bflo(v.y), sh), 0.f);
      float f3 = fmaxf(fmaf(sc, bfhi(v.y), sh), 0.f);
      float f4 = fmaxf(fmaf(sc, bflo(v.z), sh), 0.f);
      float f5 = fmaxf(fmaf(sc, bfhi(v.z), sh), 0.f);
      float f6 = fmaxf(fmaf(sc, bflo(v.w), sh), 0.f);
      float f7 = fmaxf(fmaf(sc, bfhi(v.w), sh), 0.f);
      v.x = (unsigned)f2bf(f0) | ((unsigned)f2bf(f1) << 16);
      v.y = (unsigned)f2bf(f2) | ((unsigned)f2bf(f3) << 16);
      v.z = (unsigned)f2bf(f4) | ((unsigned)f2bf(f5) << 16);
      v.w = (unsigned)f2bf(f6) | ((unsigned)f2bf(f7) << 16);
      rp[(i + ch) & 7] = v;
    }
  }
  __syncthreads();

  // ---- phase 4: fc2, register-blocked 8b x 16c per thread ----
  const int tb = tid & 31, tc = tid >> 5;
  const int b0 = tb * 8, c0 = tc * 16;
  float acc[8][16];
#pragma unroll
  for (int bi = 0; bi < 8; ++bi)
#pragma unroll
    for (int ci = 0; ci < 16; ++ci) acc[bi][ci] = 0.f;

  for (int k = 0; k < 64; ++k) {
    uint4 av = *(const uint4*)(h1 + k * 256 + b0);
    uint4 bv0 = *(const uint4*)(w2s + k * 128 + c0);
    uint4 bv1 = *(const uint4*)(w2s + k * 128 + c0 + 8);
    float a8[8], bb[16];
    a8[0] = bflo(av.x); a8[1] = bfhi(av.x); a8[2] = bflo(av.y); a8[3] = bfhi(av.y);
    a8[4] = bflo(av.z); a8[5] = bfhi(av.z); a8[6] = bflo(av.w); a8[7] = bfhi(av.w);
    bb[0] = bflo(bv0.x); bb[1] = bfhi(bv0.x); bb[2] = bflo(bv0.y); bb[3] = bfhi(bv0.y);
    bb[4] = bflo(bv0.z); bb[5] = bfhi(bv0.z); bb[6] = bflo(bv0.w); bb[7] = bfhi(bv0.w);
    bb[8] = bflo(bv1.x); bb[9] = bfhi(bv1.x); bb[10] = bflo(bv1.y); bb[11] = bfhi(bv1.y);
    bb[12] = bflo(bv1.z); bb[13] = bfhi(bv1.z); bb[14] = bflo(bv1.w); bb[15] = bfhi(bv1.w);
#pragma unroll
    for (int bi = 0; bi < 8; ++bi)
#pragma unroll
      for (int ci = 0; ci < 16; ++ci) acc[bi][ci] = fmaf(a8[bi], bb[ci], acc[bi][ci]);
  }

  // ---- phase 5: BN2 stats (shuffle-reduce over tb across 32 lanes) ----
  {
    float sv[16], qv[16];
#pragma unroll
    for (int ci = 0; ci < 16; ++ci) {
      float s = 0.f, sq = 0.f;
#pragma unroll
      for (int bi = 0; bi < 8; ++bi) {
        s += acc[bi][ci];
        sq = fmaf(acc[bi][ci], acc[bi][ci], sq);
      }
      sv[ci] = s; qv[ci] = sq;
    }
#pragma unroll
    for (int m = 1; m <= 16; m <<= 1) {
#pragma unroll
      for (int ci = 0; ci < 16; ++ci) {
        sv[ci] += __shfl_xor(sv[ci], m, 64);
        qv[ci] += __shfl_xor(qv[ci], m, 64);
      }
    }
    if (tb == 0) {
#pragma unroll
      for (int ci = 0; ci < 16; ++ci) {
        stp[(c0 + ci) * 2] = sv[ci];
        stp[(c0 + ci) * 2 + 1] = qv[ci];
      }
    }
  }
  __syncthreads();
  if (tid < 128) {
    float mu = stp[tid * 2] * (1.f / 256.f);
    float var = fmaf(-mu, mu, stp[tid * 2 + 1] * (1.f / 256.f));
    float sc = g2[tid] * rsqrtf(var + 1e-5f);
    scsh[tid * 2] = sc;
    scsh[tid * 2 + 1] = fmaf(-sc, mu, be2[tid]);
  }
  __syncthreads();
#pragma unroll
  for (int ci = 0; ci < 16; ++ci) {
    const float sc = scsh[(c0 + ci) * 2], sh = scsh[(c0 + ci) * 2 + 1];
#pragma unroll
    for (int bi = 0; bi < 8; ++bi)
      acc[bi][ci] = fmaxf(fmaf(sc, acc[bi][ci], sh), 0.f);
  }

  // ---- phase 6: fc3 partials over this thread's 16 channels ----
  {
    float lam[8][6];
#pragma unroll
    for (int bi = 0; bi < 8; ++bi)
#pragma unroll
      for (int k6 = 0; k6 < 6; ++k6) lam[bi][k6] = 0.f;
#pragma unroll
    for (int ci = 0; ci < 16; ++ci) {
      float wv[6];
#pragma unroll
      for (int k6 = 0; k6 < 6; ++k6) wv[k6] = w3s[k6 * 128 + c0 + ci];
#pragma unroll
      for (int bi = 0; bi < 8; ++bi)
#pragma unroll
        for (int k6 = 0; k6 < 6; ++k6)
          lam[bi][k6] = fmaf(acc[bi][ci], wv[k6], lam[bi][k6]);
    }
    // safe: all h1/w2s reads finished before the phase-5 barriers
#pragma unroll
    for (int bi = 0; bi < 8; ++bi)
#pragma unroll
      for (int k6 = 0; k6 < 6; ++k6)
        p3[(tc * 256 + b0 + bi) * 6 + k6] = lam[bi][k6];
  }
  __syncthreads();

  // ---- phase 7: reduce lambda, apply projection, write out ----
  {
    float lm[6];
#pragma unroll
    for (int k6 = 0; k6 < 6; ++k6) lm[k6] = b3[k6];
#pragma unroll
    for (int tcc = 0; tcc < 8; ++tcc)
#pragma unroll
      for (int k6 = 0; k6 < 6; ++k6) lm[k6] += p3[(tcc * 256 + tid) * 6 + k6];

    const float4* mp = (const float4*)(mfcc + (tid * T_LEN + t) * HDIM);
    float4 m0 = mp[0], m1 = mp[1], m2 = mp[2];
    const float x[HDIM] = {m0.x, m0.y, m0.z, m0.w, m1.x, m1.y,
                           m1.z, m1.w, m2.x, m2.y, m2.z, m2.w};
    float o[HDIM];
#pragma unroll
    for (int e = 0; e < HDIM; ++e) o[e] = x[e];
#pragma unroll
    for (int k6 = 0; k6 < 6; ++k6) {
      float pk[HDIM];
#pragma unroll
      for (int e = 0; e < HDIM; ++e) pk[e] = 0.f;
#pragma unroll
      for (int d = 0; d < HDIM; ++d)
#pragma unroll
        for (int e = 0; e < HDIM; ++e)
          pk[e] = fmaf(x[d], WI[(k6 * HDIM + d) * HDIM + e], pk[e]);
#pragma unroll
      for (int e = 0; e < HDIM; ++e) o[e] = fmaf(lm[k6], pk[e], o[e]);
    }
    float4* op4 = (float4*)(outp + (tid * T_LEN + t) * HDIM);
    op4[0] = make_float4(o[0], o[1], o[2], o[3]);
    op4[1] = make_float4(o[4], o[5], o[6], o[7]);
    op4[2] = make_float4(o[8], o[9], o[10], o[11]);
  }
}

// ============================================================================
extern "C" void kernel_launch(void* const* d_in, const int* in_sizes, int n_in,
                              void* d_out, int out_size, void* d_ws, size_t ws_size,
                              hipStream_t stream) {
  const float* mfcc = (const float*)d_in[0];
  const float* Wih = (const float*)d_in[1];
  const float* Whh = (const float*)d_in[2];
  const float* bih = (const float*)d_in[3];
  const float* bhh = (const float*)d_in[4];
  const float* w1 = (const float*)d_in[5];
  // d_in[6] fc1_b: cancels under training-mode BN
  const float* g1 = (const float*)d_in[7];
  const float* be1 = (const float*)d_in[8];
  const float* w2 = (const float*)d_in[9];
  // d_in[10] fc2_b: cancels under training-mode BN
  const float* g2 = (const float*)d_in[11];
  const float* be2 = (const float*)d_in[12];
  const float* w3 = (const float*)d_in[13];
  const float* b3 = (const float*)d_in[14];
  const float* WI = (const float*)d_in[15];

  float* x3 = (float*)d_ws;  // [T][B][12] = 12.6 MB
  float* out = (float*)d_out;

  hipLaunchKernelGGL(lstm3_kernel, dim3(NBATCH), dim3(64), 0, stream,
                     mfcc, Wih, Whh, bih, bhh, x3);
  hipLaunchKernelGGL(mlp_out_kernel, dim3(T_LEN), dim3(256), 0, stream,
                     x3, mfcc, w1, g1, be1, w2, g2, be2, w3, b3, WI, out);
}

// Round 3
// 486.416 us; speedup vs baseline: 1.2898x; 1.2898x over previous
//
#include <hip/hip_runtime.h>

#define T_LEN 1024
#define NBATCH 256
#define HDIM 12
#define PG_STRIDE 12288  // 256*48 halves per timestep

typedef __fp16 fp16x2 __attribute__((ext_vector_type(2)));

// ---------- helpers ----------
#if __has_builtin(__builtin_amdgcn_exp2f)
#define EXP2F(x) __builtin_amdgcn_exp2f(x)
#else
#define EXP2F(x) exp2f(x)
#endif
#if __has_builtin(__builtin_amdgcn_rcpf)
#define RCPF(x) __builtin_amdgcn_rcpf(x)
#else
#define RCPF(x) (1.0f / (x))
#endif

__device__ __forceinline__ float rl(float v, int lane) {
#if __has_builtin(__builtin_amdgcn_readlane)
  return __int_as_float(__builtin_amdgcn_readlane(__float_as_int(v), lane));
#else
  return __shfl(v, lane, 64);
#endif
}

template <int Q>
__device__ __forceinline__ float qb(float v) {
#if __has_builtin(__builtin_amdgcn_mov_dpp)
  return __int_as_float(__builtin_amdgcn_mov_dpp(__float_as_int(v), Q * 0x55, 0xF, 0xF, true));
#else
  return __shfl(v, (threadIdx.x & ~3) | Q, 64);
#endif
}

__device__ __forceinline__ float nl_gate(float x, float kq, float c1, float c0) {
  float e = EXP2F(kq * x);
  float r = RCPF(1.0f + e);
  return fmaf(c1, r, c0);
}
__device__ __forceinline__ float tanh_fast(float x) {
  float e = EXP2F(-2.8853900817779268f * x);
  float r = RCPF(1.0f + e);
  return fmaf(2.0f, r, -1.0f);
}

__device__ __forceinline__ float h16tof(unsigned short u) {
  union { unsigned short s; _Float16 h; } c; c.s = u; return (float)c.h;
}
__device__ __forceinline__ unsigned short f16bits(float f) {
  union { unsigned short s; _Float16 h; } c; c.h = (_Float16)f; return c.s;
}
__device__ __forceinline__ float h16lo(unsigned u) {
  union { unsigned short s; _Float16 h; } c; c.s = (unsigned short)(u & 0xffffu); return (float)c.h;
}
__device__ __forceinline__ float h16hi(unsigned u) {
  union { unsigned short s; _Float16 h; } c; c.s = (unsigned short)(u >> 16); return (float)c.h;
}
__device__ __forceinline__ unsigned pk16(float a, float b) {
#if __has_builtin(__builtin_amdgcn_cvt_pkrtz)
  fp16x2 h = __builtin_amdgcn_cvt_pkrtz(a, b);
  return __builtin_bit_cast(unsigned, h);
#else
  return (unsigned)f16bits(a) | ((unsigned)f16bits(b) << 16);
#endif
}
// (h[k][b], h[k+1][b]) pair build from two row-dwords (each dword = 2 consecutive b)
__device__ __forceinline__ unsigned plo(unsigned a, unsigned b) { return (a & 0xffffu) | (b << 16); }
__device__ __forceinline__ unsigned phi(unsigned a, unsigned b) { return (a >> 16) | (b & 0xffff0000u); }

__device__ __forceinline__ float dot2acc(unsigned a, unsigned b, float c) {
#if __has_builtin(__builtin_amdgcn_fdot2)
  return __builtin_amdgcn_fdot2(__builtin_bit_cast(fp16x2, a), __builtin_bit_cast(fp16x2, b), c, false);
#else
  return fmaf(h16lo(a), h16lo(b), fmaf(h16hi(a), h16hi(b), c));
#endif
}

// split 12-dot: two 6-FMA chains
__device__ __forceinline__ float dot12(const float* w, const float* hs, float init) {
  float e = fmaf(w[0], hs[0], init);
  float o = w[6] * hs[6];
#pragma unroll
  for (int m = 1; m < 6; ++m) e = fmaf(w[m], hs[m], e);
#pragma unroll
  for (int m = 7; m < 12; ++m) o = fmaf(w[m], hs[m], o);
  return e + o;
}

#define GATE_TAIL(AEXPR, CV, HS, HQ)                          \
  {                                                           \
    float _n = nl_gate(AEXPR, kq, c1, c0);                    \
    float _si = qb<0>(_n), _sf = qb<1>(_n);                   \
    float _tg = qb<2>(_n), _so = qb<3>(_n);                   \
    CV = fmaf(_sf, CV, _si * _tg);                            \
    HQ = _so * tanh_fast(CV);                                 \
    _Pragma("unroll")                                         \
    for (int _m = 0; _m < 12; ++_m) HS[_m] = rl(HQ, 4 * _m);  \
  }

#define SSTEP(RAW)                                                  \
  {                                                                 \
    float _pgf = h16tof(RAW);                                       \
    float _a0 = dot12(whh0, h0s, _pgf);                             \
    float _a1 = dot12(wih1, h0s, bias1) + dot12(whh1, h1s, 0.f);    \
    float _a2 = dot12(wih2, h1s, bias2) + dot12(whh2, h2s, 0.f);    \
    float _hq0, _hq1, _hq2;                                         \
    GATE_TAIL(_a0, c0v, h0s, _hq0)                                  \
    GATE_TAIL(_a1, c1v, h1s, _hq1)                                  \
    GATE_TAIL(_a2, c2v, h2s, _hq2)                                  \
    (void)_hq0; (void)_hq1;                                         \
    if (writer) *x3w = f16bits(_hq2);                               \
    x3w += 3072;                                                    \
  }

// ============================================================================
// Kernel 0: pregate  pg[t][b][laneorder 48] = f16( bih0+bhh0 + Wih0 . x[b][t] )
// ============================================================================
__global__ __launch_bounds__(64, 4) void pregate_kernel(
    const float* __restrict__ mfcc, const float* __restrict__ Wih,
    const float* __restrict__ bih, const float* __restrict__ bhh,
    unsigned short* __restrict__ pg) {
  const int b = blockIdx.x & 255;
  const int tc = blockIdx.x >> 8;  // 0..7, chunks of 128 t
  const int lane = threadIdx.x;
  const int j = lane >> 2, q = lane & 3;
  const int jj = (j < HDIM) ? j : (HDIM - 1);
  const int g = q * HDIM + jj;
  float w[HDIM];
#pragma unroll
  for (int m = 0; m < HDIM; ++m) w[m] = Wih[g * HDIM + m];
  const float bias = bih[g] + bhh[g];
  const bool wr = (lane < 48);
  const float* xb = mfcc + (b * T_LEN + tc * 128) * HDIM;
  unsigned short* out = pg + (unsigned)(tc * 128 * NBATCH + b) * 48 + lane;
#pragma unroll 2
  for (int t = 0; t < 128; ++t) {
    float acc = bias;
#pragma unroll
    for (int d = 0; d < HDIM; ++d) acc = fmaf(w[d], xb[d], acc);
    if (wr) *out = f16bits(acc);
    xb += HDIM;
    out += PG_STRIDE;
  }
}

// ============================================================================
// Kernel 1: 3-layer LSTM, 1 wave per batch element, layers pipelined.
// Branch-free main loop (prologue/epilogue peeled), unroll x2, pregate input.
// Output x3 f16 [t][b][12].
// ============================================================================
__global__ __launch_bounds__(64, 1) void lstm3_kernel(
    const unsigned short* __restrict__ pg,
    const float* __restrict__ Wih, const float* __restrict__ Whh,
    const float* __restrict__ bih, const float* __restrict__ bhh,
    unsigned short* __restrict__ x3) {
  const int b = blockIdx.x;
  const int lane = threadIdx.x & 63;
  const int j = lane >> 2, q = lane & 3;
  const int jj = (j < HDIM) ? j : (HDIM - 1);
  const int g = q * HDIM + jj;

  float whh0[HDIM], wih1[HDIM], whh1[HDIM], wih2[HDIM], whh2[HDIM];
#pragma unroll
  for (int m = 0; m < HDIM; ++m) {
    whh0[m] = Whh[g * HDIM + m];
    wih1[m] = Wih[(48 + g) * HDIM + m];
    whh1[m] = Whh[(48 + g) * HDIM + m];
    wih2[m] = Wih[(96 + g) * HDIM + m];
    whh2[m] = Whh[(96 + g) * HDIM + m];
  }
  const float bias1 = bih[48 + g] + bhh[48 + g];
  const float bias2 = bih[96 + g] + bhh[96 + g];

  const float kq = (q == 2) ? -2.8853900817779268f : -1.4426950408889634f;
  const float c1 = (q == 2) ? 2.0f : 1.0f;
  const float c0 = (q == 2) ? -1.0f : 0.0f;

  float c0v = 0.f, c1v = 0.f, c2v = 0.f;
  float h0s[HDIM], h1s[HDIM], h2s[HDIM];
#pragma unroll
  for (int m = 0; m < HDIM; ++m) { h0s[m] = 0.f; h1s[m] = 0.f; h2s[m] = 0.f; }

  const bool writer = (q == 0) && (j < HDIM);
  unsigned short* x3w = x3 + b * HDIM + jj;
  const unsigned short* pgl = pg + (unsigned)b * 48 + lane;

  unsigned short r0 = pgl[0];
  unsigned short r1 = pgl[PG_STRIDE];
  unsigned short r2 = pgl[2 * PG_STRIDE];
  unsigned short r3 = pgl[3 * PG_STRIDE];
  pgl += 4 * PG_STRIDE;

  // s=0: layer0 only (h,c all zero -> a0 = pregate)
  {
    float a0_ = h16tof(r0);
    float hq0;
    GATE_TAIL(a0_, c0v, h0s, hq0)
    (void)hq0;
  }
  // s=1: layer0 + layer1 (h1s zero -> skip whh1 part)
  {
    float a0_ = dot12(whh0, h0s, h16tof(r1));
    float a1_ = dot12(wih1, h0s, bias1);
    float hq0, hq1;
    GATE_TAIL(a0_, c0v, h0s, hq0)
    GATE_TAIL(a1_, c1v, h1s, hq1)
    (void)hq0; (void)hq1;
  }
  // main: s = 2..1023 (511 double supersteps), all layers active, no branches
  for (int it = 0; it < 511; ++it) {
    unsigned short n0 = pgl[0];
    unsigned short n1 = pgl[PG_STRIDE];
    pgl += (it < 509) ? 2 * PG_STRIDE : 0;  // clamp: never read past step 1023
    SSTEP(r2)
    SSTEP(r3)
    r2 = n0; r3 = n1;
  }
  // s=1024: layer1 (step 1023) + layer2 (step 1022)
  {
    float a1_ = dot12(wih1, h0s, bias1) + dot12(whh1, h1s, 0.f);
    float a2_ = dot12(wih2, h1s, bias2) + dot12(whh2, h2s, 0.f);
    float hq1, hq2;
    GATE_TAIL(a1_, c1v, h1s, hq1)
    GATE_TAIL(a2_, c2v, h2s, hq2)
    (void)hq1;
    if (writer) *x3w = f16bits(hq2);
    x3w += 3072;
  }
  // s=1025: layer2 (step 1023)
  {
    float a2_ = dot12(wih2, h1s, bias2) + dot12(whh2, h2s, 0.f);
    float hq2;
    GATE_TAIL(a2_, c2v, h2s, hq2)
    if (writer) *x3w = f16bits(hq2);
  }
}

// ============================================================================
// Kernel 2: per-timestep MLP + batch BN + lambda projection. 1 block / t.
// f16 staging, v_dot2_f32_f16 fc2 inner loop (k-paired).
// ============================================================================
__global__ __launch_bounds__(256, 2) void mlp_out_kernel(
    const unsigned short* __restrict__ x3, const float* __restrict__ mfcc,
    const float* __restrict__ w1, const float* __restrict__ g1,
    const float* __restrict__ be1, const float* __restrict__ w2,
    const float* __restrict__ g2, const float* __restrict__ be2,
    const float* __restrict__ w3, const float* __restrict__ b3,
    const float* __restrict__ WI, float* __restrict__ outp) {
  __shared__ __align__(16) unsigned char smem[55296];
  unsigned short* h1 = (unsigned short*)smem;        // [64][256] f16
  unsigned* w2p = (unsigned*)(smem + 32768);         // [32][128] k-paired f16x2
  float* p3 = (float*)smem;                          // [8][256][6] (alias, 48KB)
  float* w3s = (float*)(smem + 49152);               // [6][128]
  float* stp = (float*)(smem + 52224);               // stat partials
  float* scsh = (float*)(smem + 54272);              // [128][2]

  const int t = blockIdx.x;
  const int tid = threadIdx.x;

  // ---- phase 1: stage w2 k-paired + w3 ----
  for (int i = tid; i < 4096; i += 256) {
    int kp = i >> 7, c = i & 127;
    w2p[kp * 128 + c] = pk16(w2[c * 64 + 2 * kp], w2[c * 64 + 2 * kp + 1]);
  }
  for (int i = tid; i < 768; i += 256) w3s[i] = w3[i];

  // ---- phase 2: fc1 (bias cancels under BN); thread = one b ----
  {
    const unsigned short* xp = x3 + t * 3072 + tid * HDIM;
    uint2 u0 = ((const uint2*)xp)[0];
    uint2 u1 = ((const uint2*)xp)[1];
    uint2 u2 = ((const uint2*)xp)[2];
    const float x[HDIM] = {h16lo(u0.x), h16hi(u0.x), h16lo(u0.y), h16hi(u0.y),
                           h16lo(u1.x), h16hi(u1.x), h16lo(u1.y), h16hi(u1.y),
                           h16lo(u2.x), h16hi(u2.x), h16lo(u2.y), h16hi(u2.y)};
#pragma unroll 8
    for (int ch = 0; ch < 64; ++ch) {
      float a = 0.f;
#pragma unroll
      for (int d = 0; d < HDIM; ++d) a = fmaf(w1[ch * HDIM + d], x[d], a);
      h1[ch * 256 + tid] = f16bits(a);
    }
  }
  __syncthreads();

  // ---- phase 3: BN1 stats over b (on stored f16 values) ----
  {
    const int ch = tid & 63, grp = tid >> 6;
    const uint4* rp = (const uint4*)(h1 + ch * 256 + grp * 64);
    float s = 0.f, sq = 0.f;
#pragma unroll
    for (int i = 0; i < 8; ++i) {
      uint4 v = rp[(i + ch) & 7];
      float f0 = h16lo(v.x), f1 = h16hi(v.x), f2 = h16lo(v.y), f3 = h16hi(v.y);
      float f4 = h16lo(v.z), f5 = h16hi(v.z), f6 = h16lo(v.w), f7 = h16hi(v.w);
      s += ((f0 + f1) + (f2 + f3)) + ((f4 + f5) + (f6 + f7));
      sq = fmaf(f0, f0, sq); sq = fmaf(f1, f1, sq);
      sq = fmaf(f2, f2, sq); sq = fmaf(f3, f3, sq);
      sq = fmaf(f4, f4, sq); sq = fmaf(f5, f5, sq);
      sq = fmaf(f6, f6, sq); sq = fmaf(f7, f7, sq);
    }
    stp[(ch * 4 + grp) * 2] = s;
    stp[(ch * 4 + grp) * 2 + 1] = sq;
  }
  __syncthreads();
  if (tid < 64) {
    float s = 0.f, sq = 0.f;
#pragma unroll
    for (int gg = 0; gg < 4; ++gg) {
      s += stp[(tid * 4 + gg) * 2];
      sq += stp[(tid * 4 + gg) * 2 + 1];
    }
    float mu = s * (1.f / 256.f);
    float var = fmaf(-mu, mu, sq * (1.f / 256.f));
    float sc = g1[tid] * rsqrtf(var + 1e-5f);
    scsh[tid * 2] = sc;
    scsh[tid * 2 + 1] = fmaf(-sc, mu, be1[tid]);
  }
  __syncthreads();
  // ---- phase 3c: apply BN1 + relu in place ----
  {
    const int ch = tid & 63, grp = tid >> 6;
    const float sc = scsh[ch * 2], sh = scsh[ch * 2 + 1];
    uint4* rp = (uint4*)(h1 + ch * 256 + grp * 64);
#pragma unroll
    for (int i = 0; i < 8; ++i) {
      uint4 v = rp[(i + ch) & 7];
      float f0 = fmaxf(fmaf(sc, h16lo(v.x), sh), 0.f);
      float f1 = fmaxf(fmaf(sc, h16hi(v.x), sh), 0.f);
      float f2 = fmaxf(fmaf(sc, h16lo(v.y), sh), 0.f);
      float f3 = fmaxf(fmaf(sc, h16hi(v.y), sh), 0.f);
      float f4 = fmaxf(fmaf(sc, h16lo(v.z), sh), 0.f);
      float f5 = fmaxf(fmaf(sc, h16hi(v.z), sh), 0.f);
      float f6 = fmaxf(fmaf(sc, h16lo(v.w), sh), 0.f);
      float f7 = fmaxf(fmaf(sc, h16hi(v.w), sh), 0.f);
      v.x = pk16(f0, f1); v.y = pk16(f2, f3);
      v.z = pk16(f4, f5); v.w = pk16(f6, f7);
      rp[(i + ch) & 7] = v;
    }
  }
  __syncthreads();

  // ---- phase 4: fc2, 8b x 16c per thread, dot2 over k-pairs ----
  const int tb = tid & 31, tc = tid >> 5;
  const int b0 = tb * 8, cc0 = tc * 16;
  float acc[8][16];
#pragma unroll
  for (int bi = 0; bi < 8; ++bi)
#pragma unroll
    for (int ci = 0; ci < 16; ++ci) acc[bi][ci] = 0.f;

  for (int kp = 0; kp < 32; ++kp) {
    uint4 aL = *(const uint4*)(h1 + (2 * kp) * 256 + b0);
    uint4 aH = *(const uint4*)(h1 + (2 * kp + 1) * 256 + b0);
    const unsigned* wrow = w2p + kp * 128 + cc0;
    uint4 wA = ((const uint4*)wrow)[0];
    uint4 wB = ((const uint4*)wrow)[1];
    uint4 wC = ((const uint4*)wrow)[2];
    uint4 wD = ((const uint4*)wrow)[3];
    unsigned ap[8];
    ap[0] = plo(aL.x, aH.x); ap[1] = phi(aL.x, aH.x);
    ap[2] = plo(aL.y, aH.y); ap[3] = phi(aL.y, aH.y);
    ap[4] = plo(aL.z, aH.z); ap[5] = phi(aL.z, aH.z);
    ap[6] = plo(aL.w, aH.w); ap[7] = phi(aL.w, aH.w);
    const unsigned wp[16] = {wA.x, wA.y, wA.z, wA.w, wB.x, wB.y, wB.z, wB.w,
                             wC.x, wC.y, wC.z, wC.w, wD.x, wD.y, wD.z, wD.w};
#pragma unroll
    for (int bi = 0; bi < 8; ++bi)
#pragma unroll
      for (int ci = 0; ci < 16; ++ci) acc[bi][ci] = dot2acc(ap[bi], wp[ci], acc[bi][ci]);
  }

  // ---- phase 5: BN2 stats (shuffle-reduce over tb) ----
  {
    float sv[16], qv[16];
#pragma unroll
    for (int ci = 0; ci < 16; ++ci) {
      float s = 0.f, sq = 0.f;
#pragma unroll
      for (int bi = 0; bi < 8; ++bi) {
        s += acc[bi][ci];
        sq = fmaf(acc[bi][ci], acc[bi][ci], sq);
      }
      sv[ci] = s; qv[ci] = sq;
    }
#pragma unroll
    for (int m = 1; m <= 16; m <<= 1) {
#pragma unroll
      for (int ci = 0; ci < 16; ++ci) {
        sv[ci] += __shfl_xor(sv[ci], m, 64);
        qv[ci] += __shfl_xor(qv[ci], m, 64);
      }
    }
    if (tb == 0) {
#pragma unroll
      for (int ci = 0; ci < 16; ++ci) {
        stp[(cc0 + ci) * 2] = sv[ci];
        stp[(cc0 + ci) * 2 + 1] = qv[ci];
      }
    }
  }
  __syncthreads();
  if (tid < 128) {
    float mu = stp[tid * 2] * (1.f / 256.f);
    float var = fmaf(-mu, mu, stp[tid * 2 + 1] * (1.f / 256.f));
    float sc = g2[tid] * rsqrtf(var + 1e-5f);
    scsh[tid * 2] = sc;
    scsh[tid * 2 + 1] = fmaf(-sc, mu, be2[tid]);
  }
  __syncthreads();
#pragma unroll
  for (int ci = 0; ci < 16; ++ci) {
    const float sc = scsh[(cc0 + ci) * 2], sh = scsh[(cc0 + ci) * 2 + 1];
#pragma unroll
    for (int bi = 0; bi < 8; ++bi)
      acc[bi][ci] = fmaxf(fmaf(sc, acc[bi][ci], sh), 0.f);
  }

  // ---- phase 6: fc3 partials over this thread's 16 channels ----
  {
    float lam[8][6];
#pragma unroll
    for (int bi = 0; bi < 8; ++bi)
#pragma unroll
      for (int k6 = 0; k6 < 6; ++k6) lam[bi][k6] = 0.f;
#pragma unroll
    for (int ci = 0; ci < 16; ++ci) {
      float wv[6];
#pragma unroll
      for (int k6 = 0; k6 < 6; ++k6) wv[k6] = w3s[k6 * 128 + cc0 + ci];
#pragma unroll
      for (int bi = 0; bi < 8; ++bi)
#pragma unroll
        for (int k6 = 0; k6 < 6; ++k6)
          lam[bi][k6] = fmaf(acc[bi][ci], wv[k6], lam[bi][k6]);
    }
#pragma unroll
    for (int bi = 0; bi < 8; ++bi)
#pragma unroll
      for (int k6 = 0; k6 < 6; ++k6)
        p3[(tc * 256 + b0 + bi) * 6 + k6] = lam[bi][k6];
  }
  __syncthreads();

  // ---- phase 7: reduce lambda, apply projection, write out ----
  {
    float lm[6];
#pragma unroll
    for (int k6 = 0; k6 < 6; ++k6) lm[k6] = b3[k6];
#pragma unroll
    for (int tcc = 0; tcc < 8; ++tcc)
#pragma unroll
      for (int k6 = 0; k6 < 6; ++k6) lm[k6] += p3[(tcc * 256 + tid) * 6 + k6];

    const float4* mp = (const float4*)(mfcc + (tid * T_LEN + t) * HDIM);
    float4 m0 = mp[0], m1 = mp[1], m2 = mp[2];
    const float x[HDIM] = {m0.x, m0.y, m0.z, m0.w, m1.x, m1.y,
                           m1.z, m1.w, m2.x, m2.y, m2.z, m2.w};
    float o[HDIM];
#pragma unroll
    for (int e = 0; e < HDIM; ++e) o[e] = x[e];
#pragma unroll
    for (int k6 = 0; k6 < 6; ++k6) {
      float pk[HDIM];
#pragma unroll
      for (int e = 0; e < HDIM; ++e) pk[e] = 0.f;
#pragma unroll
      for (int d = 0; d < HDIM; ++d)
#pragma unroll
        for (int e = 0; e < HDIM; ++e)
          pk[e] = fmaf(x[d], WI[(k6 * HDIM + d) * HDIM + e], pk[e]);
#pragma unroll
      for (int e = 0; e < HDIM; ++e) o[e] = fmaf(lm[k6], pk[e], o[e]);
    }
    float4* op4 = (float4*)(outp + (tid * T_LEN + t) * HDIM);
    op4[0] = make_float4(o[0], o[1], o[2], o[3]);
    op4[1] = make_float4(o[4], o[5], o[6], o[7]);
    op4[2] = make_float4(o[8], o[9], o[10], o[11]);
  }
}

// ============================================================================
extern "C" void kernel_launch(void* const* d_in, const int* in_sizes, int n_in,
                              void* d_out, int out_size, void* d_ws, size_t ws_size,
                              hipStream_t stream) {
  const float* mfcc = (const float*)d_in[0];
  const float* Wih = (const float*)d_in[1];
  const float* Whh = (const float*)d_in[2];
  const float* bih = (const float*)d_in[3];
  const float* bhh = (const float*)d_in[4];
  const float* w1 = (const float*)d_in[5];
  const float* g1 = (const float*)d_in[7];
  const float* be1 = (const float*)d_in[8];
  const float* w2 = (const float*)d_in[9];
  const float* g2 = (const float*)d_in[11];
  const float* be2 = (const float*)d_in[12];
  const float* w3 = (const float*)d_in[13];
  const float* b3 = (const float*)d_in[14];
  const float* WI = (const float*)d_in[15];

  // ws layout: pregate f16 [1024][256][48] = 25,165,824 B ; x3 f16 [1024][256][12]
  unsigned short* pg = (unsigned short*)d_ws;
  unsigned short* x3 = (unsigned short*)((char*)d_ws + 25165824);
  float* out = (float*)d_out;

  hipLaunchKernelGGL(pregate_kernel, dim3(2048), dim3(64), 0, stream,
                     mfcc, Wih, bih, bhh, pg);
  hipLaunchKernelGGL(lstm3_kernel, dim3(NBATCH), dim3(64), 0, stream,
                     pg, Wih, Whh, bih, bhh, x3);
  hipLaunchKernelGGL(mlp_out_kernel, dim3(T_LEN), dim3(256), 0, stream,
                     x3, mfcc, w1, g1, be1, w2, g2, be2, w3, b3, WI, out);
}